// Round 1
// baseline (334.440 us; speedup 1.0000x reference)
//
#include <hip/hip_runtime.h>

#define B_ 32
#define C_ 64
#define H_ 128
#define W_ 128
#define HW_ (H_*W_)
#define CHW_ (C_*HW_)

// ---------------------------------------------------------------------------
// k0: precompute positional contribution of the xg/yg channels per branch.
// zpos[br][p] = pw_b[br] + sum_taps pw[br][2]*dw[br][2][t]*xg(in-bounds)
//                        + pw[br][3]*dw[br][3][t]*yg(in-bounds)
// This is data- and batch-independent: 3*16K floats, computed once.
// ---------------------------------------------------------------------------
__global__ __launch_bounds__(256) void k0_zpos(
    const float* __restrict__ dw0, const float* __restrict__ dw1,
    const float* __restrict__ dw2,
    const float* __restrict__ pw0w, const float* __restrict__ pw0b,
    const float* __restrict__ pw1w, const float* __restrict__ pw1b,
    const float* __restrict__ pw2w, const float* __restrict__ pw2b,
    float* __restrict__ zpos)
{
    int p = blockIdx.x * 256 + threadIdx.x;      // 0..16383
    int gy = p >> 7, gx = p & 127;
    const float sc = 2.0f / 127.0f;
    float z0 = pw0b[0], z1 = pw1b[0], z2 = pw2b[0];
    float px0 = pw0w[2], py0 = pw0w[3];
    float px1 = pw1w[2], py1 = pw1w[3];
    float px2 = pw2w[2], py2 = pw2w[3];

    // branch 0: k=3 d=1
    #pragma unroll
    for (int ky = 0; ky < 3; ++ky)
    #pragma unroll
    for (int kx = 0; kx < 3; ++kx) {
        int iy = gy + ky - 1, ix = gx + kx - 1;
        bool ok = ((unsigned)iy < H_) && ((unsigned)ix < W_);
        float xv = ok ? ix * sc - 1.0f : 0.0f;
        float yv = ok ? iy * sc - 1.0f : 0.0f;
        int t = ky * 3 + kx;
        z0 += px0 * dw0[18 + t] * xv + py0 * dw0[27 + t] * yv;
    }
    // branch 1: k=7 d=1
    #pragma unroll
    for (int ky = 0; ky < 7; ++ky)
    #pragma unroll
    for (int kx = 0; kx < 7; ++kx) {
        int iy = gy + ky - 3, ix = gx + kx - 3;
        bool ok = ((unsigned)iy < H_) && ((unsigned)ix < W_);
        float xv = ok ? ix * sc - 1.0f : 0.0f;
        float yv = ok ? iy * sc - 1.0f : 0.0f;
        int t = ky * 7 + kx;
        z1 += px1 * dw1[98 + t] * xv + py1 * dw1[147 + t] * yv;
    }
    // branch 2: k=7 d=2
    #pragma unroll
    for (int ky = 0; ky < 7; ++ky)
    #pragma unroll
    for (int kx = 0; kx < 7; ++kx) {
        int iy = gy + (ky - 3) * 2, ix = gx + (kx - 3) * 2;
        bool ok = ((unsigned)iy < H_) && ((unsigned)ix < W_);
        float xv = ok ? ix * sc - 1.0f : 0.0f;
        float yv = ok ? iy * sc - 1.0f : 0.0f;
        int t = ky * 7 + kx;
        z2 += px2 * dw2[98 + t] * xv + py2 * dw2[147 + t] * yv;
    }
    zpos[p]           = z0;
    zpos[HW_ + p]     = z1;
    zpos[2 * HW_ + p] = z2;
}

// ---------------------------------------------------------------------------
// k1: per-pixel channel mean & max over C=64, plus per-block pooled partials.
// Unchanged: BW-bound at ~138 MB.
// ---------------------------------------------------------------------------
__global__ __launch_bounds__(256) void k1_reduce(
    const float* __restrict__ x, float* __restrict__ avgmap,
    float* __restrict__ maxmap, float* __restrict__ partial)
{
    int t = blockIdx.x * 256 + threadIdx.x;
    int base = t * 4;
    int b = base >> 14;            // / HW_
    int q = base & (HW_ - 1);
    const float4* xp = (const float4*)(x + (size_t)b * CHW_ + q);
    float4 v = xp[0];
    float4 s = v, m = v;
    #pragma unroll 8
    for (int c = 1; c < C_; ++c) {
        float4 u = xp[c * (HW_ / 4)];
        s.x += u.x; s.y += u.y; s.z += u.z; s.w += u.w;
        m.x = fmaxf(m.x, u.x); m.y = fmaxf(m.y, u.y);
        m.z = fmaxf(m.z, u.z); m.w = fmaxf(m.w, u.w);
    }
    const float inv = 1.0f / C_;
    float4 a = make_float4(s.x * inv, s.y * inv, s.z * inv, s.w * inv);
    ((float4*)avgmap)[t] = a;
    ((float4*)maxmap)[t] = m;

    float la = a.x + a.y + a.z + a.w;
    float lm = m.x + m.y + m.z + m.w;
    #pragma unroll
    for (int o = 32; o > 0; o >>= 1) {
        la += __shfl_down(la, o);
        lm += __shfl_down(lm, o);
    }
    __shared__ float wa[4], wm[4];
    int lane = threadIdx.x & 63, wid = threadIdx.x >> 6;
    if (lane == 0) { wa[wid] = la; wm[wid] = lm; }
    __syncthreads();
    if (threadIdx.x == 0) {
        partial[2 * blockIdx.x]     = wa[0] + wa[1] + wa[2] + wa[3];
        partial[2 * blockIdx.x + 1] = wm[0] + wm[1] + wm[2] + wm[3];
    }
}

// ---------------------------------------------------------------------------
// k2: sum 16 partials per batch, router MLP 4->8->3 + softmax.
// Also precompute 1/T once (saves log1p+exp per pixel in k34).
// ---------------------------------------------------------------------------
__global__ void k2_router(const float* __restrict__ partial,
                          const float* __restrict__ rw1, const float* __restrict__ rb1,
                          const float* __restrict__ rw2, const float* __restrict__ rb2,
                          const float* __restrict__ t_raw,
                          float* __restrict__ rwout)
{
    int b = threadIdx.x;
    if (b >= B_) return;
    if (b == 0)
        rwout[96] = 1.0f / (log1pf(expf(t_raw[0])) + 1e-6f);
    float s0 = 0.0f, s1 = 0.0f;
    #pragma unroll
    for (int i = 0; i < 16; ++i) {
        s0 += partial[2 * (b * 16 + i)];
        s1 += partial[2 * (b * 16 + i) + 1];
    }
    float p0 = s0 * (1.0f / HW_);
    float p1 = s1 * (1.0f / HW_);
    float hid[8];
    #pragma unroll
    for (int j = 0; j < 8; ++j)
        hid[j] = fmaxf(0.0f, rb1[j] + rw1[j * 4] * p0 + rw1[j * 4 + 1] * p1);
    float lg[3];
    #pragma unroll
    for (int i = 0; i < 3; ++i) {
        float acc = rb2[i];
        #pragma unroll
        for (int j = 0; j < 8; ++j) acc += hid[j] * rw2[i * 8 + j];
        lg[i] = acc;
    }
    float mx = fmaxf(lg[0], fmaxf(lg[1], lg[2]));
    float e0 = expf(lg[0] - mx), e1 = expf(lg[1] - mx), e2 = expf(lg[2] - mx);
    float inv = 1.0f / (e0 + e1 + e2);
    rwout[b * 3 + 0] = e0 * inv;
    rwout[b * 3 + 1] = e1 * inv;
    rwout[b * 3 + 2] = e2 * inv;
}

// ---------------------------------------------------------------------------
// k34: fused branches + combine + sigmoid + Y = x*sa.
// Block = 4 output rows (512 thr), LDS 16 rows x 140 cols per map (±6 halo,
// 6 zero-pad cols -> conv padding free). Conv now only touches avg/max
// (positional part precomputed in zpos): 2 LDS reads + 2 FMA per tap,
// no branches in the hot loop. b0 reuses b1's row loads.
// ---------------------------------------------------------------------------
__global__ __launch_bounds__(512) void k34_branches_apply(
    const float* __restrict__ x,
    const float* __restrict__ avgmap, const float* __restrict__ maxmap,
    const float* __restrict__ dw0, const float* __restrict__ dw1,
    const float* __restrict__ dw2,
    const float* __restrict__ pw0w, const float* __restrict__ pw1w,
    const float* __restrict__ pw2w,
    const float* __restrict__ zpos, const float* __restrict__ rw,
    float* __restrict__ y, float* __restrict__ sa_out)
{
    __shared__ float sA[16][140];
    __shared__ float sM[16][140];
    __shared__ float wA0[9], wM0[9];
    __shared__ float wA1[49], wM1[49], wA2[49], wM2[49];
    __shared__ __align__(16) float ssa[512];

    int b  = blockIdx.y;
    int y0 = blockIdx.x * 4;               // first of 4 output rows
    int tix = threadIdx.x;
    const float* am = avgmap + (size_t)b * HW_;
    const float* mm = maxmap + (size_t)b * HW_;

    // stage 16 rows x 128 cols of each map (float4), rows y0-6 .. y0+9
    {
        int r = tix >> 5, c4 = tix & 31;   // 512 threads = 16*32 exactly
        int gy = y0 - 6 + r;
        bool ok = (unsigned)gy < H_;
        float4 av = ok ? ((const float4*)(am + gy * W_))[c4]
                       : make_float4(0.f, 0.f, 0.f, 0.f);
        float4 mv = ok ? ((const float4*)(mm + gy * W_))[c4]
                       : make_float4(0.f, 0.f, 0.f, 0.f);
        float* pa = &sA[r][6 + c4 * 4];
        float* pm = &sM[r][6 + c4 * 4];
        pa[0] = av.x; pa[1] = av.y; pa[2] = av.z; pa[3] = av.w;
        pm[0] = mv.x; pm[1] = mv.y; pm[2] = mv.z; pm[3] = mv.w;
    }
    // zero pad columns (6 each side, 16 rows): 192 entries per map
    if (tix < 16 * 12) {
        int r = tix / 12, c = tix % 12;
        int cc = (c < 6) ? c : (134 + c - 6);
        sA[r][cc] = 0.0f;
        sM[r][cc] = 0.0f;
    }
    // folded weights (avg/max channels only)
    if (tix < 9)  { wA0[tix] = pw0w[0] * dw0[tix];
                    wM0[tix] = pw0w[1] * dw0[9 + tix]; }
    if (tix < 49) { wA1[tix] = pw1w[0] * dw1[tix];
                    wM1[tix] = pw1w[1] * dw1[49 + tix];
                    wA2[tix] = pw2w[0] * dw2[tix];
                    wM2[tix] = pw2w[1] * dw2[49 + tix]; }
    __syncthreads();

    int ly = tix >> 7;                     // 0..3
    int lx = tix & 127;                    // 0..127
    int gy = y0 + ly;
    int pidx = gy * W_ + lx;

    float z0 = zpos[pidx];
    float z1 = zpos[HW_ + pidx];
    float z2 = zpos[2 * HW_ + pidx];

    // branches 0 (k=3 d=1, reuses row loads) and 1 (k=7 d=1)
    #pragma unroll
    for (int ky = 0; ky < 7; ++ky) {
        const float* ra = &sA[ly + 3 + ky][lx + 3];
        const float* rm = &sM[ly + 3 + ky][lx + 3];
        float av[7], mv[7];
        #pragma unroll
        for (int j = 0; j < 7; ++j) { av[j] = ra[j]; mv[j] = rm[j]; }
        #pragma unroll
        for (int j = 0; j < 7; ++j) {
            int t = ky * 7 + j;
            z1 += wA1[t] * av[j] + wM1[t] * mv[j];
        }
        if (ky >= 2 && ky <= 4) {
            #pragma unroll
            for (int j = 2; j <= 4; ++j) {
                int t = (ky - 2) * 3 + (j - 2);
                z0 += wA0[t] * av[j] + wM0[t] * mv[j];
            }
        }
    }
    // branch 2: k=7 d=2 (rows ly+2*ky, cols lx+2*kx)
    #pragma unroll
    for (int ky = 0; ky < 7; ++ky) {
        const float* ra = &sA[ly + 2 * ky][lx];
        const float* rm = &sM[ly + 2 * ky][lx];
        #pragma unroll
        for (int kx = 0; kx < 7; ++kx) {
            int t = ky * 7 + kx;
            z2 += wA2[t] * ra[2 * kx] + wM2[t] * rm[2 * kx];
        }
    }

    float wl = rw[b * 3] * z0 + rw[b * 3 + 1] * z1 + rw[b * 3 + 2] * z2;
    float s = 1.0f / (1.0f + expf(-wl * rw[96]));
    ssa[tix] = s;
    sa_out[(size_t)b * HW_ + pidx] = s;
    __syncthreads();

    // apply: tile is 4 rows x 128 = 2 KiB per channel, contiguous.
    // 8 waves; wave w handles channels w, w+8, ...; lane-striped float4.
    int wid  = tix >> 6;                   // 0..7
    int lane = tix & 63;                   // 0..63
    float4 sv0 = ((const float4*)ssa)[lane];
    float4 sv1 = ((const float4*)ssa)[64 + lane];
    const float* xt = x + (size_t)b * CHW_ + y0 * W_;
    float*       yt = y + (size_t)b * CHW_ + y0 * W_;
    #pragma unroll 4
    for (int k = 0; k < 8; ++k) {
        int c = wid + k * 8;
        const float4* xp = (const float4*)(xt + c * HW_);
        float4*       yp = (float4*)(yt + c * HW_);
        float4 a0 = xp[lane];
        float4 a1 = xp[64 + lane];
        yp[lane]      = make_float4(a0.x * sv0.x, a0.y * sv0.y,
                                    a0.z * sv0.z, a0.w * sv0.w);
        yp[64 + lane] = make_float4(a1.x * sv1.x, a1.y * sv1.y,
                                    a1.z * sv1.z, a1.w * sv1.w);
    }
}

extern "C" void kernel_launch(void* const* d_in, const int* in_sizes, int n_in,
                              void* d_out, int out_size, void* d_ws, size_t ws_size,
                              hipStream_t stream)
{
    const float* x     = (const float*)d_in[0];
    const float* dw0   = (const float*)d_in[1];
    const float* dw1   = (const float*)d_in[2];
    const float* dw2   = (const float*)d_in[3];
    const float* pw0w  = (const float*)d_in[4];
    const float* pw0b  = (const float*)d_in[5];
    const float* pw1w  = (const float*)d_in[6];
    const float* pw1b  = (const float*)d_in[7];
    const float* pw2w  = (const float*)d_in[8];
    const float* pw2b  = (const float*)d_in[9];
    const float* rw1   = (const float*)d_in[10];
    const float* rb1   = (const float*)d_in[11];
    const float* rw2   = (const float*)d_in[12];
    const float* rb2   = (const float*)d_in[13];
    const float* t_raw = (const float*)d_in[14];

    float* ws      = (float*)d_ws;
    float* avgmap  = ws;                       // 524288 floats
    float* maxmap  = ws + 524288;              // 524288 floats
    float* partial = ws + 1048576;             // 1024 floats (512 blocks x 2)
    float* rw      = ws + 1049600;             // 97 floats (32x3 + invT)
    float* zpos    = ws + 1049728;             // 3*16384 floats

    float* Y  = (float*)d_out;
    float* sa = Y + (size_t)B_ * CHW_;         // 524288 floats

    k0_zpos<<<HW_ / 256, 256, 0, stream>>>(
        dw0, dw1, dw2, pw0w, pw0b, pw1w, pw1b, pw2w, pw2b, zpos);
    k1_reduce<<<B_ * HW_ / 4 / 256, 256, 0, stream>>>(x, avgmap, maxmap, partial);
    k2_router<<<1, 64, 0, stream>>>(partial, rw1, rb1, rw2, rb2, t_raw, rw);

    dim3 g34(H_ / 4, B_);
    k34_branches_apply<<<g34, 512, 0, stream>>>(
        x, avgmap, maxmap, dw0, dw1, dw2,
        pw0w, pw1w, pw2w, zpos, rw, Y, sa);
}

// Round 2
// 320.093 us; speedup vs baseline: 1.0448x; 1.0448x over previous
//
#include <hip/hip_runtime.h>

#define B_ 32
#define C_ 64
#define H_ 128
#define W_ 128
#define HW_ (H_*W_)
#define CHW_ (C_*HW_)

typedef float f4 __attribute__((ext_vector_type(4)));

// ---------------------------------------------------------------------------
// k0: precompute positional contribution of the xg/yg channels per branch.
// Data- and batch-independent: 3*16K floats, computed once.
// ---------------------------------------------------------------------------
__global__ __launch_bounds__(256) void k0_zpos(
    const float* __restrict__ dw0, const float* __restrict__ dw1,
    const float* __restrict__ dw2,
    const float* __restrict__ pw0w, const float* __restrict__ pw0b,
    const float* __restrict__ pw1w, const float* __restrict__ pw1b,
    const float* __restrict__ pw2w, const float* __restrict__ pw2b,
    float* __restrict__ zpos)
{
    int p = blockIdx.x * 256 + threadIdx.x;      // 0..16383
    int gy = p >> 7, gx = p & 127;
    const float sc = 2.0f / 127.0f;
    float z0 = pw0b[0], z1 = pw1b[0], z2 = pw2b[0];
    float px0 = pw0w[2], py0 = pw0w[3];
    float px1 = pw1w[2], py1 = pw1w[3];
    float px2 = pw2w[2], py2 = pw2w[3];

    #pragma unroll
    for (int ky = 0; ky < 3; ++ky)
    #pragma unroll
    for (int kx = 0; kx < 3; ++kx) {
        int iy = gy + ky - 1, ix = gx + kx - 1;
        bool ok = ((unsigned)iy < H_) && ((unsigned)ix < W_);
        float xv = ok ? ix * sc - 1.0f : 0.0f;
        float yv = ok ? iy * sc - 1.0f : 0.0f;
        int t = ky * 3 + kx;
        z0 += px0 * dw0[18 + t] * xv + py0 * dw0[27 + t] * yv;
    }
    #pragma unroll
    for (int ky = 0; ky < 7; ++ky)
    #pragma unroll
    for (int kx = 0; kx < 7; ++kx) {
        int iy = gy + ky - 3, ix = gx + kx - 3;
        bool ok = ((unsigned)iy < H_) && ((unsigned)ix < W_);
        float xv = ok ? ix * sc - 1.0f : 0.0f;
        float yv = ok ? iy * sc - 1.0f : 0.0f;
        int t = ky * 7 + kx;
        z1 += px1 * dw1[98 + t] * xv + py1 * dw1[147 + t] * yv;
    }
    #pragma unroll
    for (int ky = 0; ky < 7; ++ky)
    #pragma unroll
    for (int kx = 0; kx < 7; ++kx) {
        int iy = gy + (ky - 3) * 2, ix = gx + (kx - 3) * 2;
        bool ok = ((unsigned)iy < H_) && ((unsigned)ix < W_);
        float xv = ok ? ix * sc - 1.0f : 0.0f;
        float yv = ok ? iy * sc - 1.0f : 0.0f;
        int t = ky * 7 + kx;
        z2 += px2 * dw2[98 + t] * xv + py2 * dw2[147 + t] * yv;
    }
    zpos[p]           = z0;
    zpos[HW_ + p]     = z1;
    zpos[2 * HW_ + p] = z2;
}

// ---------------------------------------------------------------------------
// k1: per-pixel channel mean & max over C=64, plus per-block pooled partials.
// BW-bound at ~138 MB; also warms L3 with x for k4.
// ---------------------------------------------------------------------------
__global__ __launch_bounds__(256) void k1_reduce(
    const float* __restrict__ x, float* __restrict__ avgmap,
    float* __restrict__ maxmap, float* __restrict__ partial)
{
    int t = blockIdx.x * 256 + threadIdx.x;
    int base = t * 4;
    int b = base >> 14;            // / HW_
    int q = base & (HW_ - 1);
    const float4* xp = (const float4*)(x + (size_t)b * CHW_ + q);
    float4 v = xp[0];
    float4 s = v, m = v;
    #pragma unroll 8
    for (int c = 1; c < C_; ++c) {
        float4 u = xp[c * (HW_ / 4)];
        s.x += u.x; s.y += u.y; s.z += u.z; s.w += u.w;
        m.x = fmaxf(m.x, u.x); m.y = fmaxf(m.y, u.y);
        m.z = fmaxf(m.z, u.z); m.w = fmaxf(m.w, u.w);
    }
    const float inv = 1.0f / C_;
    float4 a = make_float4(s.x * inv, s.y * inv, s.z * inv, s.w * inv);
    ((float4*)avgmap)[t] = a;
    ((float4*)maxmap)[t] = m;

    float la = a.x + a.y + a.z + a.w;
    float lm = m.x + m.y + m.z + m.w;
    #pragma unroll
    for (int o = 32; o > 0; o >>= 1) {
        la += __shfl_down(la, o);
        lm += __shfl_down(lm, o);
    }
    __shared__ float wa[4], wm[4];
    int lane = threadIdx.x & 63, wid = threadIdx.x >> 6;
    if (lane == 0) { wa[wid] = la; wm[wid] = lm; }
    __syncthreads();
    if (threadIdx.x == 0) {
        partial[2 * blockIdx.x]     = wa[0] + wa[1] + wa[2] + wa[3];
        partial[2 * blockIdx.x + 1] = wm[0] + wm[1] + wm[2] + wm[3];
    }
}

// ---------------------------------------------------------------------------
// k2: sum 16 partials per batch, router MLP 4->8->3 + softmax. Also 1/T.
// ---------------------------------------------------------------------------
__global__ void k2_router(const float* __restrict__ partial,
                          const float* __restrict__ rw1, const float* __restrict__ rb1,
                          const float* __restrict__ rw2, const float* __restrict__ rb2,
                          const float* __restrict__ t_raw,
                          float* __restrict__ rwout)
{
    int b = threadIdx.x;
    if (b >= B_) return;
    if (b == 0)
        rwout[96] = 1.0f / (log1pf(expf(t_raw[0])) + 1e-6f);
    float s0 = 0.0f, s1 = 0.0f;
    #pragma unroll
    for (int i = 0; i < 16; ++i) {
        s0 += partial[2 * (b * 16 + i)];
        s1 += partial[2 * (b * 16 + i) + 1];
    }
    float p0 = s0 * (1.0f / HW_);
    float p1 = s1 * (1.0f / HW_);
    float hid[8];
    #pragma unroll
    for (int j = 0; j < 8; ++j)
        hid[j] = fmaxf(0.0f, rb1[j] + rw1[j * 4] * p0 + rw1[j * 4 + 1] * p1);
    float lg[3];
    #pragma unroll
    for (int i = 0; i < 3; ++i) {
        float acc = rb2[i];
        #pragma unroll
        for (int j = 0; j < 8; ++j) acc += hid[j] * rw2[i * 8 + j];
        lg[i] = acc;
    }
    float mx = fmaxf(lg[0], fmaxf(lg[1], lg[2]));
    float e0 = expf(lg[0] - mx), e1 = expf(lg[1] - mx), e2 = expf(lg[2] - mx);
    float inv = 1.0f / (e0 + e1 + e2);
    rwout[b * 3 + 0] = e0 * inv;
    rwout[b * 3 + 1] = e1 * inv;
    rwout[b * 3 + 2] = e2 * inv;
}

// ---------------------------------------------------------------------------
// k3: conv branches + combine + sigmoid -> sa only. 256 thr, 2 output rows
// (round-0 proven geometry). Conv touches only avg/max (positional part in
// zpos): 2 LDS reads + 2 FMA per tap, no branches in the hot loop.
// ---------------------------------------------------------------------------
__global__ __launch_bounds__(256) void k3_conv(
    const float* __restrict__ avgmap, const float* __restrict__ maxmap,
    const float* __restrict__ dw0, const float* __restrict__ dw1,
    const float* __restrict__ dw2,
    const float* __restrict__ pw0w, const float* __restrict__ pw1w,
    const float* __restrict__ pw2w,
    const float* __restrict__ zpos, const float* __restrict__ rw,
    float* __restrict__ sa_out)
{
    __shared__ float sA[14][140];
    __shared__ float sM[14][140];
    __shared__ float wA0[9], wM0[9];
    __shared__ float wA1[49], wM1[49], wA2[49], wM2[49];

    int b  = blockIdx.y;
    int y0 = blockIdx.x * 2;               // first of 2 output rows
    int tix = threadIdx.x;
    const float* am = avgmap + (size_t)b * HW_;
    const float* mm = maxmap + (size_t)b * HW_;

    // stage 14 rows x 128 cols of each map (float4), rows y0-6 .. y0+7
    for (int idx = tix; idx < 14 * 32; idx += 256) {
        int r = idx >> 5, c4 = idx & 31;
        int gy = y0 - 6 + r;
        bool ok = (unsigned)gy < H_;
        float4 av = ok ? ((const float4*)(am + gy * W_))[c4]
                       : make_float4(0.f, 0.f, 0.f, 0.f);
        float4 mv = ok ? ((const float4*)(mm + gy * W_))[c4]
                       : make_float4(0.f, 0.f, 0.f, 0.f);
        float* pa = &sA[r][6 + c4 * 4];
        float* pm = &sM[r][6 + c4 * 4];
        pa[0] = av.x; pa[1] = av.y; pa[2] = av.z; pa[3] = av.w;
        pm[0] = mv.x; pm[1] = mv.y; pm[2] = mv.z; pm[3] = mv.w;
    }
    // zero pad columns (6 each side, 14 rows)
    for (int idx = tix; idx < 14 * 12; idx += 256) {
        int r = idx / 12, c = idx % 12;
        int cc = (c < 6) ? c : (134 + c - 6);
        sA[r][cc] = 0.0f;
        sM[r][cc] = 0.0f;
    }
    // folded weights (avg/max channels only)
    if (tix < 9)  { wA0[tix] = pw0w[0] * dw0[tix];
                    wM0[tix] = pw0w[1] * dw0[9 + tix]; }
    if (tix < 49) { wA1[tix] = pw1w[0] * dw1[tix];
                    wM1[tix] = pw1w[1] * dw1[49 + tix];
                    wA2[tix] = pw2w[0] * dw2[tix];
                    wM2[tix] = pw2w[1] * dw2[49 + tix]; }
    __syncthreads();

    int ly = tix >> 7;                     // 0..1
    int lx = tix & 127;                    // 0..127
    int gy = y0 + ly;
    int pidx = gy * W_ + lx;

    float z0 = zpos[pidx];
    float z1 = zpos[HW_ + pidx];
    float z2 = zpos[2 * HW_ + pidx];

    // branches 0 (k=3 d=1, reuses b1's row loads) and 1 (k=7 d=1)
    #pragma unroll
    for (int ky = 0; ky < 7; ++ky) {
        const float* ra = &sA[ly + 3 + ky][lx + 3];
        const float* rm = &sM[ly + 3 + ky][lx + 3];
        float av[7], mv[7];
        #pragma unroll
        for (int j = 0; j < 7; ++j) { av[j] = ra[j]; mv[j] = rm[j]; }
        #pragma unroll
        for (int j = 0; j < 7; ++j) {
            int t = ky * 7 + j;
            z1 += wA1[t] * av[j] + wM1[t] * mv[j];
        }
        if (ky >= 2 && ky <= 4) {
            #pragma unroll
            for (int j = 2; j <= 4; ++j) {
                int t = (ky - 2) * 3 + (j - 2);
                z0 += wA0[t] * av[j] + wM0[t] * mv[j];
            }
        }
    }
    // branch 2: k=7 d=2
    #pragma unroll
    for (int ky = 0; ky < 7; ++ky) {
        const float* ra = &sA[ly + 2 * ky][lx];
        const float* rm = &sM[ly + 2 * ky][lx];
        #pragma unroll
        for (int kx = 0; kx < 7; ++kx) {
            int t = ky * 7 + kx;
            z2 += wA2[t] * ra[2 * kx] + wM2[t] * rm[2 * kx];
        }
    }

    float wl = rw[b * 3] * z0 + rw[b * 3 + 1] * z1 + rw[b * 3 + 2] * z2;
    float s = 1.0f / (1.0f + expf(-wl * rw[96]));
    sa_out[(size_t)b * HW_ + pidx] = s;
}

// ---------------------------------------------------------------------------
// k4: Y = x * sa. Pure streaming, no barriers, 2048 blocks (8/CU).
// Each block: one 1024-pixel tile x 16 channels. Non-temporal Y stores keep
// the L3-resident x from being evicted by the 134 MB write stream.
// ---------------------------------------------------------------------------
__global__ __launch_bounds__(256) void k4_apply(
    const float* __restrict__ x, const float* __restrict__ sa,
    float* __restrict__ y)
{
    int tile = blockIdx.x;                 // 0..511 : 1024-pixel tile
    int cg   = blockIdx.y;                 // 0..3   : 16-channel group
    int b  = tile >> 4;
    int p4 = (tile & 15) * 256 + threadIdx.x;   // float4 index in HW/4

    f4 sv = ((const f4*)(sa + (size_t)b * HW_))[p4];
    const f4* xb = (const f4*)(x + (size_t)b * CHW_) + p4;
    f4*       yb = (f4*)(y + (size_t)b * CHW_) + p4;

    #pragma unroll 4
    for (int k = 0; k < 16; ++k) {
        int c = cg * 16 + k;
        f4 v = xb[c * (HW_ / 4)];
        f4 r = v * sv;
        __builtin_nontemporal_store(r, &yb[c * (HW_ / 4)]);
    }
}

extern "C" void kernel_launch(void* const* d_in, const int* in_sizes, int n_in,
                              void* d_out, int out_size, void* d_ws, size_t ws_size,
                              hipStream_t stream)
{
    const float* x     = (const float*)d_in[0];
    const float* dw0   = (const float*)d_in[1];
    const float* dw1   = (const float*)d_in[2];
    const float* dw2   = (const float*)d_in[3];
    const float* pw0w  = (const float*)d_in[4];
    const float* pw0b  = (const float*)d_in[5];
    const float* pw1w  = (const float*)d_in[6];
    const float* pw1b  = (const float*)d_in[7];
    const float* pw2w  = (const float*)d_in[8];
    const float* pw2b  = (const float*)d_in[9];
    const float* rw1   = (const float*)d_in[10];
    const float* rb1   = (const float*)d_in[11];
    const float* rw2   = (const float*)d_in[12];
    const float* rb2   = (const float*)d_in[13];
    const float* t_raw = (const float*)d_in[14];

    float* ws      = (float*)d_ws;
    float* avgmap  = ws;                       // 524288 floats
    float* maxmap  = ws + 524288;              // 524288 floats
    float* partial = ws + 1048576;             // 1024 floats
    float* rw      = ws + 1049600;             // 97 floats (32x3 + invT)
    float* zpos    = ws + 1049728;             // 3*16384 floats

    float* Y  = (float*)d_out;
    float* sa = Y + (size_t)B_ * CHW_;         // 524288 floats

    k0_zpos<<<HW_ / 256, 256, 0, stream>>>(
        dw0, dw1, dw2, pw0w, pw0b, pw1w, pw1b, pw2w, pw2b, zpos);
    k1_reduce<<<B_ * HW_ / 4 / 256, 256, 0, stream>>>(x, avgmap, maxmap, partial);
    k2_router<<<1, 64, 0, stream>>>(partial, rw1, rb1, rw2, rb2, t_raw, rw);

    dim3 g3(H_ / 2, B_);
    k3_conv<<<g3, 256, 0, stream>>>(
        avgmap, maxmap, dw0, dw1, dw2, pw0w, pw1w, pw2w, zpos, rw, sa);

    dim3 g4(B_ * HW_ / 4 / 256, 4);
    k4_apply<<<g4, 256, 0, stream>>>(x, sa, Y);
}

// Round 3
// 294.993 us; speedup vs baseline: 1.1337x; 1.0851x over previous
//
#include <hip/hip_runtime.h>

#define B_ 32
#define C_ 64
#define H_ 128
#define W_ 128
#define HW_ (H_*W_)
#define CHW_ (C_*HW_)

typedef float f4 __attribute__((ext_vector_type(4)));

// ---------------------------------------------------------------------------
// k0: precompute positional contribution of the xg/yg channels per branch.
// Data- and batch-independent: 3*16K floats, computed once.
// ---------------------------------------------------------------------------
__global__ __launch_bounds__(256) void k0_zpos(
    const float* __restrict__ dw0, const float* __restrict__ dw1,
    const float* __restrict__ dw2,
    const float* __restrict__ pw0w, const float* __restrict__ pw0b,
    const float* __restrict__ pw1w, const float* __restrict__ pw1b,
    const float* __restrict__ pw2w, const float* __restrict__ pw2b,
    float* __restrict__ zpos)
{
    int p = blockIdx.x * 256 + threadIdx.x;      // 0..16383
    int gy = p >> 7, gx = p & 127;
    const float sc = 2.0f / 127.0f;
    float z0 = pw0b[0], z1 = pw1b[0], z2 = pw2b[0];
    float px0 = pw0w[2], py0 = pw0w[3];
    float px1 = pw1w[2], py1 = pw1w[3];
    float px2 = pw2w[2], py2 = pw2w[3];

    #pragma unroll
    for (int ky = 0; ky < 3; ++ky)
    #pragma unroll
    for (int kx = 0; kx < 3; ++kx) {
        int iy = gy + ky - 1, ix = gx + kx - 1;
        bool ok = ((unsigned)iy < H_) && ((unsigned)ix < W_);
        float xv = ok ? ix * sc - 1.0f : 0.0f;
        float yv = ok ? iy * sc - 1.0f : 0.0f;
        int t = ky * 3 + kx;
        z0 += px0 * dw0[18 + t] * xv + py0 * dw0[27 + t] * yv;
    }
    #pragma unroll
    for (int ky = 0; ky < 7; ++ky)
    #pragma unroll
    for (int kx = 0; kx < 7; ++kx) {
        int iy = gy + ky - 3, ix = gx + kx - 3;
        bool ok = ((unsigned)iy < H_) && ((unsigned)ix < W_);
        float xv = ok ? ix * sc - 1.0f : 0.0f;
        float yv = ok ? iy * sc - 1.0f : 0.0f;
        int t = ky * 7 + kx;
        z1 += px1 * dw1[98 + t] * xv + py1 * dw1[147 + t] * yv;
    }
    #pragma unroll
    for (int ky = 0; ky < 7; ++ky)
    #pragma unroll
    for (int kx = 0; kx < 7; ++kx) {
        int iy = gy + (ky - 3) * 2, ix = gx + (kx - 3) * 2;
        bool ok = ((unsigned)iy < H_) && ((unsigned)ix < W_);
        float xv = ok ? ix * sc - 1.0f : 0.0f;
        float yv = ok ? iy * sc - 1.0f : 0.0f;
        int t = ky * 7 + kx;
        z2 += px2 * dw2[98 + t] * xv + py2 * dw2[147 + t] * yv;
    }
    zpos[p]           = z0;
    zpos[HW_ + p]     = z1;
    zpos[2 * HW_ + p] = z2;
}

// ---------------------------------------------------------------------------
// k1: per-pixel channel mean & max over C=64, plus per-block pooled partials.
// BW-bound at ~138 MB; also warms L3 with x for k34's apply phase.
// ---------------------------------------------------------------------------
__global__ __launch_bounds__(256) void k1_reduce(
    const float* __restrict__ x, float* __restrict__ avgmap,
    float* __restrict__ maxmap, float* __restrict__ partial)
{
    int t = blockIdx.x * 256 + threadIdx.x;
    int base = t * 4;
    int b = base >> 14;            // / HW_
    int q = base & (HW_ - 1);
    const float4* xp = (const float4*)(x + (size_t)b * CHW_ + q);
    float4 v = xp[0];
    float4 s = v, m = v;
    #pragma unroll 8
    for (int c = 1; c < C_; ++c) {
        float4 u = xp[c * (HW_ / 4)];
        s.x += u.x; s.y += u.y; s.z += u.z; s.w += u.w;
        m.x = fmaxf(m.x, u.x); m.y = fmaxf(m.y, u.y);
        m.z = fmaxf(m.z, u.z); m.w = fmaxf(m.w, u.w);
    }
    const float inv = 1.0f / C_;
    float4 a = make_float4(s.x * inv, s.y * inv, s.z * inv, s.w * inv);
    ((float4*)avgmap)[t] = a;
    ((float4*)maxmap)[t] = m;

    float la = a.x + a.y + a.z + a.w;
    float lm = m.x + m.y + m.z + m.w;
    #pragma unroll
    for (int o = 32; o > 0; o >>= 1) {
        la += __shfl_down(la, o);
        lm += __shfl_down(lm, o);
    }
    __shared__ float wa[4], wm[4];
    int lane = threadIdx.x & 63, wid = threadIdx.x >> 6;
    if (lane == 0) { wa[wid] = la; wm[wid] = lm; }
    __syncthreads();
    if (threadIdx.x == 0) {
        partial[2 * blockIdx.x]     = wa[0] + wa[1] + wa[2] + wa[3];
        partial[2 * blockIdx.x + 1] = wm[0] + wm[1] + wm[2] + wm[3];
    }
}

// ---------------------------------------------------------------------------
// k34: fused conv branches + router (inline) + sigmoid + apply. 256 thr,
// 2 output rows (baseline-proven geometry: conv of some blocks overlaps
// apply of others). Router MLP computed redundantly per block by thread 0
// (~50 FLOPs) -> k2 kernel and its device-wide drain eliminated.
// Y / sa are write-once -> non-temporal stores, so the 134 MB write stream
// does not evict the L3-resident x between k1 and the apply phase.
// ---------------------------------------------------------------------------
__global__ __launch_bounds__(256) void k34_fused(
    const float* __restrict__ x,
    const float* __restrict__ avgmap, const float* __restrict__ maxmap,
    const float* __restrict__ dw0, const float* __restrict__ dw1,
    const float* __restrict__ dw2,
    const float* __restrict__ pw0w, const float* __restrict__ pw1w,
    const float* __restrict__ pw2w,
    const float* __restrict__ zpos,
    const float* __restrict__ partial,
    const float* __restrict__ rw1, const float* __restrict__ rb1,
    const float* __restrict__ rw2, const float* __restrict__ rb2,
    const float* __restrict__ t_raw,
    float* __restrict__ y, float* __restrict__ sa_out)
{
    __shared__ float sA[14][140];
    __shared__ float sM[14][140];
    __shared__ float wA0[9], wM0[9];
    __shared__ float wA1[49], wM1[49], wA2[49], wM2[49];
    __shared__ __align__(16) float ssa[256];
    __shared__ float sRW[4];               // rw0, rw1, rw2, 1/T

    int b  = blockIdx.y;
    int y0 = blockIdx.x * 2;               // first of 2 output rows
    int tix = threadIdx.x;
    const float* am = avgmap + (size_t)b * HW_;
    const float* mm = maxmap + (size_t)b * HW_;

    // stage 14 rows x 128 cols of each map (float4), rows y0-6 .. y0+7
    for (int idx = tix; idx < 14 * 32; idx += 256) {
        int r = idx >> 5, c4 = idx & 31;
        int gy = y0 - 6 + r;
        bool ok = (unsigned)gy < H_;
        float4 av = ok ? ((const float4*)(am + gy * W_))[c4]
                       : make_float4(0.f, 0.f, 0.f, 0.f);
        float4 mv = ok ? ((const float4*)(mm + gy * W_))[c4]
                       : make_float4(0.f, 0.f, 0.f, 0.f);
        float* pa = &sA[r][6 + c4 * 4];
        float* pm = &sM[r][6 + c4 * 4];
        pa[0] = av.x; pa[1] = av.y; pa[2] = av.z; pa[3] = av.w;
        pm[0] = mv.x; pm[1] = mv.y; pm[2] = mv.z; pm[3] = mv.w;
    }
    // zero pad columns (6 each side, 14 rows)
    for (int idx = tix; idx < 14 * 12; idx += 256) {
        int r = idx / 12, c = idx % 12;
        int cc = (c < 6) ? c : (134 + c - 6);
        sA[r][cc] = 0.0f;
        sM[r][cc] = 0.0f;
    }
    // folded weights (avg/max channels only)
    if (tix < 9)  { wA0[tix] = pw0w[0] * dw0[tix];
                    wM0[tix] = pw0w[1] * dw0[9 + tix]; }
    if (tix < 49) { wA1[tix] = pw1w[0] * dw1[tix];
                    wM1[tix] = pw1w[1] * dw1[49 + tix];
                    wA2[tix] = pw2w[0] * dw2[tix];
                    wM2[tix] = pw2w[1] * dw2[49 + tix]; }
    // inline router for this batch (thread 0; hidden under staging)
    if (tix == 0) {
        float s0 = 0.0f, s1 = 0.0f;
        #pragma unroll
        for (int i = 0; i < 16; ++i) {
            s0 += partial[2 * (b * 16 + i)];
            s1 += partial[2 * (b * 16 + i) + 1];
        }
        float p0 = s0 * (1.0f / HW_);
        float p1 = s1 * (1.0f / HW_);
        float hid[8];
        #pragma unroll
        for (int j = 0; j < 8; ++j)
            hid[j] = fmaxf(0.0f, rb1[j] + rw1[j * 4] * p0 + rw1[j * 4 + 1] * p1);
        float lg[3];
        #pragma unroll
        for (int i = 0; i < 3; ++i) {
            float acc = rb2[i];
            #pragma unroll
            for (int j = 0; j < 8; ++j) acc += hid[j] * rw2[i * 8 + j];
            lg[i] = acc;
        }
        float mx = fmaxf(lg[0], fmaxf(lg[1], lg[2]));
        float e0 = expf(lg[0] - mx), e1 = expf(lg[1] - mx), e2 = expf(lg[2] - mx);
        float inv = 1.0f / (e0 + e1 + e2);
        sRW[0] = e0 * inv;
        sRW[1] = e1 * inv;
        sRW[2] = e2 * inv;
        sRW[3] = 1.0f / (log1pf(expf(t_raw[0])) + 1e-6f);
    }
    __syncthreads();

    int ly = tix >> 7;                     // 0..1
    int lx = tix & 127;                    // 0..127
    int gy = y0 + ly;
    int pidx = gy * W_ + lx;

    float z0 = zpos[pidx];
    float z1 = zpos[HW_ + pidx];
    float z2 = zpos[2 * HW_ + pidx];

    // branches 0 (k=3 d=1, reuses b1's row loads) and 1 (k=7 d=1)
    #pragma unroll
    for (int ky = 0; ky < 7; ++ky) {
        const float* ra = &sA[ly + 3 + ky][lx + 3];
        const float* rm = &sM[ly + 3 + ky][lx + 3];
        float av[7], mv[7];
        #pragma unroll
        for (int j = 0; j < 7; ++j) { av[j] = ra[j]; mv[j] = rm[j]; }
        #pragma unroll
        for (int j = 0; j < 7; ++j) {
            int t = ky * 7 + j;
            z1 += wA1[t] * av[j] + wM1[t] * mv[j];
        }
        if (ky >= 2 && ky <= 4) {
            #pragma unroll
            for (int j = 2; j <= 4; ++j) {
                int t = (ky - 2) * 3 + (j - 2);
                z0 += wA0[t] * av[j] + wM0[t] * mv[j];
            }
        }
    }
    // branch 2: k=7 d=2
    #pragma unroll
    for (int ky = 0; ky < 7; ++ky) {
        const float* ra = &sA[ly + 2 * ky][lx];
        const float* rm = &sM[ly + 2 * ky][lx];
        #pragma unroll
        for (int kx = 0; kx < 7; ++kx) {
            int t = ky * 7 + kx;
            z2 += wA2[t] * ra[2 * kx] + wM2[t] * rm[2 * kx];
        }
    }

    float wl = sRW[0] * z0 + sRW[1] * z1 + sRW[2] * z2;
    float s = 1.0f / (1.0f + expf(-wl * sRW[3]));
    ssa[tix] = s;
    __builtin_nontemporal_store(s, &sa_out[(size_t)b * HW_ + pidx]);
    __syncthreads();

    // apply: per channel the 256-pixel tile is one contiguous 1 KiB chunk.
    // wave w handles channels w, w+4, ...; lane-striped float4.
    int wid  = tix >> 6;                   // 0..3
    int lane = tix & 63;                   // 0..63
    f4 sv = ((const f4*)ssa)[lane];
    const float* xt = x + (size_t)b * CHW_ + y0 * W_;
    float*       yt = y + (size_t)b * CHW_ + y0 * W_;
    #pragma unroll 4
    for (int k = 0; k < 16; ++k) {
        int c = wid + k * 4;
        f4 xv = *((const f4*)(xt + c * HW_) + lane);
        f4 r  = xv * sv;
        __builtin_nontemporal_store(r, (f4*)(yt + c * HW_) + lane);
    }
}

extern "C" void kernel_launch(void* const* d_in, const int* in_sizes, int n_in,
                              void* d_out, int out_size, void* d_ws, size_t ws_size,
                              hipStream_t stream)
{
    const float* x     = (const float*)d_in[0];
    const float* dw0   = (const float*)d_in[1];
    const float* dw1   = (const float*)d_in[2];
    const float* dw2   = (const float*)d_in[3];
    const float* pw0w  = (const float*)d_in[4];
    const float* pw0b  = (const float*)d_in[5];
    const float* pw1w  = (const float*)d_in[6];
    const float* pw1b  = (const float*)d_in[7];
    const float* pw2w  = (const float*)d_in[8];
    const float* pw2b  = (const float*)d_in[9];
    const float* rw1   = (const float*)d_in[10];
    const float* rb1   = (const float*)d_in[11];
    const float* rw2   = (const float*)d_in[12];
    const float* rb2   = (const float*)d_in[13];
    const float* t_raw = (const float*)d_in[14];

    float* ws      = (float*)d_ws;
    float* avgmap  = ws;                       // 524288 floats
    float* maxmap  = ws + 524288;              // 524288 floats
    float* partial = ws + 1048576;             // 1024 floats
    float* zpos    = ws + 1049600;             // 3*16384 floats

    float* Y  = (float*)d_out;
    float* sa = Y + (size_t)B_ * CHW_;         // 524288 floats

    k0_zpos<<<HW_ / 256, 256, 0, stream>>>(
        dw0, dw1, dw2, pw0w, pw0b, pw1w, pw1b, pw2w, pw2b, zpos);
    k1_reduce<<<B_ * HW_ / 4 / 256, 256, 0, stream>>>(x, avgmap, maxmap, partial);

    dim3 g34(H_ / 2, B_);
    k34_fused<<<g34, 256, 0, stream>>>(
        x, avgmap, maxmap, dw0, dw1, dw2,
        pw0w, pw1w, pw2w, zpos,
        partial, rw1, rb1, rw2, rb2, t_raw, Y, sa);
}

// Round 4
// 293.703 us; speedup vs baseline: 1.1387x; 1.0044x over previous
//
#include <hip/hip_runtime.h>

#define B_ 32
#define C_ 64
#define H_ 128
#define W_ 128
#define HW_ (H_*W_)
#define CHW_ (C_*HW_)

typedef float f4 __attribute__((ext_vector_type(4)));

// ---------------------------------------------------------------------------
// k0: precompute positional contribution of the xg/yg channels per branch.
// Data- and batch-independent: 3*16K floats, computed once.
// ---------------------------------------------------------------------------
__global__ __launch_bounds__(256) void k0_zpos(
    const float* __restrict__ dw0, const float* __restrict__ dw1,
    const float* __restrict__ dw2,
    const float* __restrict__ pw0w, const float* __restrict__ pw0b,
    const float* __restrict__ pw1w, const float* __restrict__ pw1b,
    const float* __restrict__ pw2w, const float* __restrict__ pw2b,
    float* __restrict__ zpos)
{
    int p = blockIdx.x * 256 + threadIdx.x;      // 0..16383
    int gy = p >> 7, gx = p & 127;
    const float sc = 2.0f / 127.0f;
    float z0 = pw0b[0], z1 = pw1b[0], z2 = pw2b[0];
    float px0 = pw0w[2], py0 = pw0w[3];
    float px1 = pw1w[2], py1 = pw1w[3];
    float px2 = pw2w[2], py2 = pw2w[3];

    #pragma unroll
    for (int ky = 0; ky < 3; ++ky)
    #pragma unroll
    for (int kx = 0; kx < 3; ++kx) {
        int iy = gy + ky - 1, ix = gx + kx - 1;
        bool ok = ((unsigned)iy < H_) && ((unsigned)ix < W_);
        float xv = ok ? ix * sc - 1.0f : 0.0f;
        float yv = ok ? iy * sc - 1.0f : 0.0f;
        int t = ky * 3 + kx;
        z0 += px0 * dw0[18 + t] * xv + py0 * dw0[27 + t] * yv;
    }
    #pragma unroll
    for (int ky = 0; ky < 7; ++ky)
    #pragma unroll
    for (int kx = 0; kx < 7; ++kx) {
        int iy = gy + ky - 3, ix = gx + kx - 3;
        bool ok = ((unsigned)iy < H_) && ((unsigned)ix < W_);
        float xv = ok ? ix * sc - 1.0f : 0.0f;
        float yv = ok ? iy * sc - 1.0f : 0.0f;
        int t = ky * 7 + kx;
        z1 += px1 * dw1[98 + t] * xv + py1 * dw1[147 + t] * yv;
    }
    #pragma unroll
    for (int ky = 0; ky < 7; ++ky)
    #pragma unroll
    for (int kx = 0; kx < 7; ++kx) {
        int iy = gy + (ky - 3) * 2, ix = gx + (kx - 3) * 2;
        bool ok = ((unsigned)iy < H_) && ((unsigned)ix < W_);
        float xv = ok ? ix * sc - 1.0f : 0.0f;
        float yv = ok ? iy * sc - 1.0f : 0.0f;
        int t = ky * 7 + kx;
        z2 += px2 * dw2[98 + t] * xv + py2 * dw2[147 + t] * yv;
    }
    zpos[p]           = z0;
    zpos[HW_ + p]     = z1;
    zpos[2 * HW_ + p] = z2;
}

// ---------------------------------------------------------------------------
// k1: per-pixel channel mean & max over C=64, plus per-block pooled partials.
// BW-bound at ~138 MB; also warms L3 with x for k34's apply phase.
// ---------------------------------------------------------------------------
__global__ __launch_bounds__(256) void k1_reduce(
    const float* __restrict__ x, float* __restrict__ avgmap,
    float* __restrict__ maxmap, float* __restrict__ partial)
{
    int t = blockIdx.x * 256 + threadIdx.x;
    int base = t * 4;
    int b = base >> 14;            // / HW_
    int q = base & (HW_ - 1);
    const float4* xp = (const float4*)(x + (size_t)b * CHW_ + q);
    float4 v = xp[0];
    float4 s = v, m = v;
    #pragma unroll 8
    for (int c = 1; c < C_; ++c) {
        float4 u = xp[c * (HW_ / 4)];
        s.x += u.x; s.y += u.y; s.z += u.z; s.w += u.w;
        m.x = fmaxf(m.x, u.x); m.y = fmaxf(m.y, u.y);
        m.z = fmaxf(m.z, u.z); m.w = fmaxf(m.w, u.w);
    }
    const float inv = 1.0f / C_;
    float4 a = make_float4(s.x * inv, s.y * inv, s.z * inv, s.w * inv);
    ((float4*)avgmap)[t] = a;
    ((float4*)maxmap)[t] = m;

    float la = a.x + a.y + a.z + a.w;
    float lm = m.x + m.y + m.z + m.w;
    #pragma unroll
    for (int o = 32; o > 0; o >>= 1) {
        la += __shfl_down(la, o);
        lm += __shfl_down(lm, o);
    }
    __shared__ float wa[4], wm[4];
    int lane = threadIdx.x & 63, wid = threadIdx.x >> 6;
    if (lane == 0) { wa[wid] = la; wm[wid] = lm; }
    __syncthreads();
    if (threadIdx.x == 0) {
        partial[2 * blockIdx.x]     = wa[0] + wa[1] + wa[2] + wa[3];
        partial[2 * blockIdx.x + 1] = wm[0] + wm[1] + wm[2] + wm[3];
    }
}

// ---------------------------------------------------------------------------
// k34: fused conv branches + router (inline) + sigmoid + apply.
// T14 async-split: the 16 float4 x loads for the apply phase are ISSUED
// right after the first barrier, BEFORE the conv. The conv is LDS+reg only
// (zpos is loaded early and consumed only after the conv, so no global
// load lands in the issue->consume window to force an early vmcnt drain).
// The second __syncthreads' vmcnt(0) drain is covered by the conv.
// ---------------------------------------------------------------------------
__global__ __launch_bounds__(256) void k34_fused(
    const float* __restrict__ x,
    const float* __restrict__ avgmap, const float* __restrict__ maxmap,
    const float* __restrict__ dw0, const float* __restrict__ dw1,
    const float* __restrict__ dw2,
    const float* __restrict__ pw0w, const float* __restrict__ pw1w,
    const float* __restrict__ pw2w,
    const float* __restrict__ zpos,
    const float* __restrict__ partial,
    const float* __restrict__ rw1, const float* __restrict__ rb1,
    const float* __restrict__ rw2, const float* __restrict__ rb2,
    const float* __restrict__ t_raw,
    float* __restrict__ y, float* __restrict__ sa_out)
{
    __shared__ float sA[14][140];
    __shared__ float sM[14][140];
    __shared__ float wA0[9], wM0[9];
    __shared__ float wA1[49], wM1[49], wA2[49], wM2[49];
    __shared__ __align__(16) float ssa[256];
    __shared__ float sRW[4];               // rw0, rw1, rw2, 1/T

    int b  = blockIdx.y;
    int y0 = blockIdx.x * 2;               // first of 2 output rows
    int tix = threadIdx.x;
    const float* am = avgmap + (size_t)b * HW_;
    const float* mm = maxmap + (size_t)b * HW_;

    // stage 14 rows x 128 cols of each map (float4), rows y0-6 .. y0+7
    for (int idx = tix; idx < 14 * 32; idx += 256) {
        int r = idx >> 5, c4 = idx & 31;
        int gy = y0 - 6 + r;
        bool ok = (unsigned)gy < H_;
        float4 av = ok ? ((const float4*)(am + gy * W_))[c4]
                       : make_float4(0.f, 0.f, 0.f, 0.f);
        float4 mv = ok ? ((const float4*)(mm + gy * W_))[c4]
                       : make_float4(0.f, 0.f, 0.f, 0.f);
        float* pa = &sA[r][6 + c4 * 4];
        float* pm = &sM[r][6 + c4 * 4];
        pa[0] = av.x; pa[1] = av.y; pa[2] = av.z; pa[3] = av.w;
        pm[0] = mv.x; pm[1] = mv.y; pm[2] = mv.z; pm[3] = mv.w;
    }
    // zero pad columns (6 each side, 14 rows)
    for (int idx = tix; idx < 14 * 12; idx += 256) {
        int r = idx / 12, c = idx % 12;
        int cc = (c < 6) ? c : (134 + c - 6);
        sA[r][cc] = 0.0f;
        sM[r][cc] = 0.0f;
    }
    // folded weights (avg/max channels only)
    if (tix < 9)  { wA0[tix] = pw0w[0] * dw0[tix];
                    wM0[tix] = pw0w[1] * dw0[9 + tix]; }
    if (tix < 49) { wA1[tix] = pw1w[0] * dw1[tix];
                    wM1[tix] = pw1w[1] * dw1[49 + tix];
                    wA2[tix] = pw2w[0] * dw2[tix];
                    wM2[tix] = pw2w[1] * dw2[49 + tix]; }
    // inline router for this batch (thread 0; hidden under staging)
    if (tix == 0) {
        float s0 = 0.0f, s1 = 0.0f;
        #pragma unroll
        for (int i = 0; i < 16; ++i) {
            s0 += partial[2 * (b * 16 + i)];
            s1 += partial[2 * (b * 16 + i) + 1];
        }
        float p0 = s0 * (1.0f / HW_);
        float p1 = s1 * (1.0f / HW_);
        float hid[8];
        #pragma unroll
        for (int j = 0; j < 8; ++j)
            hid[j] = fmaxf(0.0f, rb1[j] + rw1[j * 4] * p0 + rw1[j * 4 + 1] * p1);
        float lg[3];
        #pragma unroll
        for (int i = 0; i < 3; ++i) {
            float acc = rb2[i];
            #pragma unroll
            for (int j = 0; j < 8; ++j) acc += hid[j] * rw2[i * 8 + j];
            lg[i] = acc;
        }
        float mx = fmaxf(lg[0], fmaxf(lg[1], lg[2]));
        float e0 = expf(lg[0] - mx), e1 = expf(lg[1] - mx), e2 = expf(lg[2] - mx);
        float inv = 1.0f / (e0 + e1 + e2);
        sRW[0] = e0 * inv;
        sRW[1] = e1 * inv;
        sRW[2] = e2 * inv;
        sRW[3] = 1.0f / (log1pf(expf(t_raw[0])) + 1e-6f);
    }

    int ly = tix >> 7;                     // 0..1
    int lx = tix & 127;                    // 0..127
    int gy = y0 + ly;
    int pidx = gy * W_ + lx;

    // zpos loads issued early; consumed only AFTER the conv (see below)
    float z0 = zpos[pidx];
    float z1 = zpos[HW_ + pidx];
    float z2 = zpos[2 * HW_ + pidx];

    __syncthreads();                       // drains staging loads only

    // -------- T14: issue all apply-phase x loads now, consume after conv --
    int wid  = tix >> 6;                   // 0..3
    int lane = tix & 63;                   // 0..63
    const float* xt = x + (size_t)b * CHW_ + y0 * W_;
    float*       yt = y + (size_t)b * CHW_ + y0 * W_;
    f4 xv[16];
    #pragma unroll
    for (int k = 0; k < 16; ++k)
        xv[k] = *((const f4*)(xt + (wid + k * 4) * HW_) + lane);

    // -------- conv (LDS + registers only) --------------------------------
    float c0 = 0.0f, c1 = 0.0f, c2 = 0.0f;

    // branches 0 (k=3 d=1, reuses b1's row loads) and 1 (k=7 d=1)
    #pragma unroll
    for (int ky = 0; ky < 7; ++ky) {
        const float* ra = &sA[ly + 3 + ky][lx + 3];
        const float* rm = &sM[ly + 3 + ky][lx + 3];
        float av[7], mv[7];
        #pragma unroll
        for (int j = 0; j < 7; ++j) { av[j] = ra[j]; mv[j] = rm[j]; }
        #pragma unroll
        for (int j = 0; j < 7; ++j) {
            int t = ky * 7 + j;
            c1 += wA1[t] * av[j] + wM1[t] * mv[j];
        }
        if (ky >= 2 && ky <= 4) {
            #pragma unroll
            for (int j = 2; j <= 4; ++j) {
                int t = (ky - 2) * 3 + (j - 2);
                c0 += wA0[t] * av[j] + wM0[t] * mv[j];
            }
        }
    }
    // branch 2: k=7 d=2
    #pragma unroll
    for (int ky = 0; ky < 7; ++ky) {
        const float* ra = &sA[ly + 2 * ky][lx];
        const float* rm = &sM[ly + 2 * ky][lx];
        #pragma unroll
        for (int kx = 0; kx < 7; ++kx) {
            int t = ky * 7 + kx;
            c2 += wA2[t] * ra[2 * kx] + wM2[t] * rm[2 * kx];
        }
    }

    float wl = sRW[0] * (z0 + c0) + sRW[1] * (z1 + c1) + sRW[2] * (z2 + c2);
    float s = 1.0f / (1.0f + expf(-wl * sRW[3]));
    ssa[tix] = s;
    __builtin_nontemporal_store(s, &sa_out[(size_t)b * HW_ + pidx]);
    __syncthreads();                       // x loads have landed by now

    // -------- apply from registers ---------------------------------------
    f4 sv = ((const f4*)ssa)[lane];
    #pragma unroll
    for (int k = 0; k < 16; ++k) {
        f4 r = xv[k] * sv;
        __builtin_nontemporal_store(r, (f4*)(yt + (wid + k * 4) * HW_) + lane);
    }
}

extern "C" void kernel_launch(void* const* d_in, const int* in_sizes, int n_in,
                              void* d_out, int out_size, void* d_ws, size_t ws_size,
                              hipStream_t stream)
{
    const float* x     = (const float*)d_in[0];
    const float* dw0   = (const float*)d_in[1];
    const float* dw1   = (const float*)d_in[2];
    const float* dw2   = (const float*)d_in[3];
    const float* pw0w  = (const float*)d_in[4];
    const float* pw0b  = (const float*)d_in[5];
    const float* pw1w  = (const float*)d_in[6];
    const float* pw1b  = (const float*)d_in[7];
    const float* pw2w  = (const float*)d_in[8];
    const float* pw2b  = (const float*)d_in[9];
    const float* rw1   = (const float*)d_in[10];
    const float* rb1   = (const float*)d_in[11];
    const float* rw2   = (const float*)d_in[12];
    const float* rb2   = (const float*)d_in[13];
    const float* t_raw = (const float*)d_in[14];

    float* ws      = (float*)d_ws;
    float* avgmap  = ws;                       // 524288 floats
    float* maxmap  = ws + 524288;              // 524288 floats
    float* partial = ws + 1048576;             // 1024 floats
    float* zpos    = ws + 1049600;             // 3*16384 floats

    float* Y  = (float*)d_out;
    float* sa = Y + (size_t)B_ * CHW_;         // 524288 floats

    k1_reduce<<<B_ * HW_ / 4 / 256, 256, 0, stream>>>(x, avgmap, maxmap, partial);
    k0_zpos<<<HW_ / 256, 256, 0, stream>>>(
        dw0, dw1, dw2, pw0w, pw0b, pw1w, pw1b, pw2w, pw2b, zpos);

    dim3 g34(H_ / 2, B_);
    k34_fused<<<g34, 256, 0, stream>>>(
        x, avgmap, maxmap, dw0, dw1, dw2,
        pw0w, pw1w, pw2w, zpos,
        partial, rw1, rb1, rw2, rb2, t_raw, Y, sa);
}